// Round 1
// baseline (2380.553 us; speedup 1.0000x reference)
//
#include <hip/hip_runtime.h>
#include <hip/hip_bf16.h>
#include <math.h>

#define N_NODES  200000
#define NNZ_CNT  3200000
#define N_GRAPHS 256

// ---------------- CSR build ----------------
__global__ void count_rows_k(const int* __restrict__ rows, int nnz, int* __restrict__ cnt) {
  int i = blockIdx.x * 256 + threadIdx.x;
  if (i < nnz) atomicAdd(&cnt[rows[i]], 1);
}

__global__ void scan_local_k(const int* __restrict__ cnt, int n, int* __restrict__ out, int* __restrict__ blk) {
  __shared__ int wsum[4];
  int t = threadIdx.x;
  int base = blockIdx.x * 2048 + t * 8;
  int v[8]; int s = 0;
  #pragma unroll
  for (int j = 0; j < 8; ++j) { int idx = base + j; v[j] = (idx < n) ? cnt[idx] : 0; s += v[j]; }
  int lane = t & 63, w = t >> 6;
  int x = s;
  #pragma unroll
  for (int d = 1; d < 64; d <<= 1) { int y = __shfl_up(x, d); if (lane >= d) x += y; }
  if (lane == 63) wsum[w] = x;
  __syncthreads();
  int wofs = 0;
  for (int i2 = 0; i2 < w; ++i2) wofs += wsum[i2];
  int run = wofs + x - s;
  #pragma unroll
  for (int j = 0; j < 8; ++j) { int idx = base + j; if (idx < n) out[idx] = run; run += v[j]; }
  if (t == 255) blk[blockIdx.x] = wofs + x;
}

__global__ void scan_blocks_k(int* __restrict__ blk, int B) {
  __shared__ int wsum[2];
  int t = threadIdx.x;
  int v = (t < B) ? blk[t] : 0;
  int lane = t & 63, w = t >> 6;
  int x = v;
  #pragma unroll
  for (int d = 1; d < 64; d <<= 1) { int y = __shfl_up(x, d); if (lane >= d) x += y; }
  if (lane == 63) wsum[w] = x;
  __syncthreads();
  int wofs = (w == 1) ? wsum[0] : 0;
  if (t < B) blk[t] = wofs + x - v;
}

__global__ void scan_add_k(int* __restrict__ out, const int* __restrict__ blk, int n,
                           int* __restrict__ nxt, int total) {
  int i = blockIdx.x * 256 + threadIdx.x;
  if (i < n) { int v = out[i] + blk[i >> 11]; out[i] = v; nxt[i] = v; }
  if (i == 0) out[n] = total;
}

__global__ void scatter_k(const int* __restrict__ rows, const int* __restrict__ cols,
                          const float* __restrict__ vals, int nnz, int* __restrict__ nxt,
                          int* __restrict__ cs, float* __restrict__ vs) {
  int i = blockIdx.x * 256 + threadIdx.x;
  if (i < nnz) {
    int r = rows[i];
    int p = atomicAdd(&nxt[r], 1);
    cs[p] = cols[i];
    vs[p] = vals[i];
  }
}

// ---------------- layer-1 GEMM: [N,128] @ [128,32] (heads concat) ----------------
__global__ __launch_bounds__(256) void gemm1_k(const float* __restrict__ X, const float* __restrict__ W,
                                               float* __restrict__ H, int n) {
  __shared__ float Ws[128 * 32];
  __shared__ float Xs[128 * 33];
  int t = threadIdx.x;
  for (int idx = t; idx < 4096; idx += 256) {
    int hh = idx >> 11, rem = idx & 2047, k = rem >> 4, f = rem & 15;
    Ws[k * 32 + hh * 16 + f] = W[idx];
  }
  int r0 = blockIdx.x * 128;
  int rt = t >> 3, ct = t & 7;
  float acc[4][4];
  #pragma unroll
  for (int i = 0; i < 4; ++i)
    #pragma unroll
    for (int j = 0; j < 4; ++j) acc[i][j] = 0.f;
  for (int k0 = 0; k0 < 128; k0 += 32) {
    __syncthreads();
    #pragma unroll
    for (int pp = 0; pp < 4; ++pp) {
      int f4 = pp * 256 + t;
      int row = f4 >> 3, q = f4 & 7;
      int rr = r0 + row;
      float4 v = make_float4(0.f, 0.f, 0.f, 0.f);
      if (rr < n) v = *(const float4*)&X[rr * 128 + k0 + q * 4];
      Xs[row * 33 + q * 4 + 0] = v.x;
      Xs[row * 33 + q * 4 + 1] = v.y;
      Xs[row * 33 + q * 4 + 2] = v.z;
      Xs[row * 33 + q * 4 + 3] = v.w;
    }
    __syncthreads();
    #pragma unroll
    for (int kk = 0; kk < 32; ++kk) {
      int k = k0 + kk;
      float4 wv = *(const float4*)&Ws[k * 32 + ct * 4];
      float xv[4];
      #pragma unroll
      for (int i = 0; i < 4; ++i) xv[i] = Xs[(rt * 4 + i) * 33 + kk];
      #pragma unroll
      for (int i = 0; i < 4; ++i) {
        acc[i][0] += xv[i] * wv.x;
        acc[i][1] += xv[i] * wv.y;
        acc[i][2] += xv[i] * wv.z;
        acc[i][3] += xv[i] * wv.w;
      }
    }
  }
  #pragma unroll
  for (int i = 0; i < 4; ++i) {
    int rr = r0 + rt * 4 + i;
    if (rr < n)
      *(float4*)&H[rr * 32 + ct * 4] = make_float4(acc[i][0], acc[i][1], acc[i][2], acc[i][3]);
  }
}

// ---------------- per-row attention scores s1,s2 for layer 1 ----------------
__global__ void s_l1_k(const float* __restrict__ H, const float* __restrict__ a1,
                       const float* __restrict__ a2, float* __restrict__ s, int n) {
  int i = blockIdx.x * 256 + threadIdx.x;
  if (i >= n) return;
  const float* h = H + (size_t)i * 32;
  float s1u = 0.f, s2u = 0.f, s1d = 0.f, s2d = 0.f;
  #pragma unroll
  for (int f = 0; f < 16; ++f) {
    float au = fabsf(h[f]);
    s1u += au * a1[f]; s2u += au * a2[f];
    float ad = fabsf(h[16 + f]);
    s1d += ad * a1[16 + f]; s2d += ad * a2[16 + f];
  }
  s[i] = s1u; s[n + i] = s2u; s[2 * n + i] = s1d; s[3 * n + i] = s2d;
}

// ---------------- fused sparse softmax + SpMM, f_out=16 (one wave / row) ----------------
__global__ __launch_bounds__(256) void spmm16_k(const int* __restrict__ rp, const int* __restrict__ cs,
    const float* __restrict__ vs, const float* __restrict__ H, const float* __restrict__ s1,
    const float* __restrict__ s2, float* __restrict__ out, int n) {
  int wid = (blockIdx.x * 256 + threadIdx.x) >> 6;
  int lane = threadIdx.x & 63;
  if (wid >= n) return;
  int beg = rp[wid], end = rp[wid + 1];
  float s1r = s1[wid];
  float vmax = -1e30f;
  for (int e = beg + lane; e < end; e += 64) vmax = fmaxf(vmax, s1r + s2[cs[e]]);
  #pragma unroll
  for (int d = 32; d; d >>= 1) vmax = fmaxf(vmax, __shfl_xor(vmax, d));
  float esum = 0.f;
  for (int e = beg + lane; e < end; e += 64) esum += __expf(s1r + s2[cs[e]] - vmax);
  #pragma unroll
  for (int d = 32; d; d >>= 1) esum += __shfl_xor(esum, d);
  float inv = (end > beg) ? 1.f / esum : 0.f;
  int j = lane >> 4, f = lane & 15;
  float acc = 0.f;
  for (int e0 = beg; e0 < end; e0 += 4) {
    int e = e0 + j;
    if (e < end) {
      int c = cs[e];
      float att = __expf(s1r + s2[c] - vmax) * inv * vs[e];
      acc += att * H[(size_t)c * 32 + f];
    }
  }
  acc += __shfl_xor(acc, 16);
  acc += __shfl_xor(acc, 32);
  if (lane < 16) out[(size_t)wid * 32 + f] = fmaxf(acc, 0.f);
}

// ---------------- fused sparse softmax + SpMM, f_out=64 (one wave / row, lane=feature) ----------------
template <int MODE>
__global__ __launch_bounds__(256) void spmm64_k(const int* __restrict__ rp, const int* __restrict__ cs,
    const float* __restrict__ vs, const float* __restrict__ H, const float* __restrict__ s1,
    const float* __restrict__ s2, float* __restrict__ out, int n) {
  int wid = (blockIdx.x * 256 + threadIdx.x) >> 6;
  int lane = threadIdx.x & 63;
  if (wid >= n) return;
  int beg = rp[wid], end = rp[wid + 1];
  float s1r = s1[wid];
  float vmax = -1e30f;
  for (int e = beg + lane; e < end; e += 64) vmax = fmaxf(vmax, s1r + s2[cs[e]]);
  #pragma unroll
  for (int d = 32; d; d >>= 1) vmax = fmaxf(vmax, __shfl_xor(vmax, d));
  float esum = 0.f;
  for (int e = beg + lane; e < end; e += 64) esum += __expf(s1r + s2[cs[e]] - vmax);
  #pragma unroll
  for (int d = 32; d; d >>= 1) esum += __shfl_xor(esum, d);
  float inv = (end > beg) ? 1.f / esum : 0.f;
  float acc = 0.f;
  for (int e = beg; e < end; ++e) {
    int c = cs[e];
    float att = __expf(s1r + s2[c] - vmax) * inv * vs[e];
    acc += att * H[(size_t)c * 64 + lane];
  }
  if (MODE == 0) {
    out[(size_t)wid * 64 + lane] = acc;
  } else {
    float v = out[(size_t)wid * 64 + lane] + acc;
    out[(size_t)wid * 64 + lane] = fmaxf(v, 0.f);
  }
}

// ---------------- layer-2 GEMM [N,32]@[32,32] + fused s1/s2 ----------------
__global__ __launch_bounds__(256) void gemm2_k(const float* __restrict__ X, const float* __restrict__ W,
    const float* __restrict__ a1, const float* __restrict__ a2, float* __restrict__ H,
    float* __restrict__ s, int n) {
  __shared__ float Ws[32 * 32];
  int t = threadIdx.x;
  for (int idx = t; idx < 1024; idx += 256) {
    int hh = idx >> 9, rem = idx & 511, k = rem >> 4, f = rem & 15;
    Ws[k * 32 + hh * 16 + f] = W[idx];
  }
  __syncthreads();
  int i = blockIdx.x * 256 + t;
  if (i >= n) return;
  float x[32];
  const float4* xp = (const float4*)(X + (size_t)i * 32);
  #pragma unroll
  for (int q = 0; q < 8; ++q) { float4 v = xp[q]; x[q*4] = v.x; x[q*4+1] = v.y; x[q*4+2] = v.z; x[q*4+3] = v.w; }
  float acc[32];
  #pragma unroll
  for (int c = 0; c < 32; ++c) acc[c] = 0.f;
  #pragma unroll 8
  for (int k = 0; k < 32; ++k) {
    float xk = x[k];
    #pragma unroll
    for (int c = 0; c < 32; ++c) acc[c] += xk * Ws[k * 32 + c];
  }
  float s1u = 0.f, s2u = 0.f, s1d = 0.f, s2d = 0.f;
  #pragma unroll
  for (int f = 0; f < 16; ++f) {
    float au = fabsf(acc[f]);      s1u += au * a1[f];      s2u += au * a2[f];
    float ad = fabsf(acc[16 + f]); s1d += ad * a1[16 + f]; s2d += ad * a2[16 + f];
  }
  float4* hp = (float4*)(H + (size_t)i * 32);
  #pragma unroll
  for (int q = 0; q < 8; ++q) hp[q] = make_float4(acc[q*4], acc[q*4+1], acc[q*4+2], acc[q*4+3]);
  s[i] = s1u; s[n + i] = s2u; s[2 * n + i] = s1d; s[3 * n + i] = s2d;
}

// ---------------- layer-4 GEMM [N,32]@[32,64] per head + fused s1/s2 ----------------
__global__ __launch_bounds__(256) void gemm4_k(const float* __restrict__ X, const float* __restrict__ W,
    const float* __restrict__ a1, const float* __restrict__ a2, float* __restrict__ H,
    float* __restrict__ s1o, float* __restrict__ s2o, int n) {
  __shared__ float Ws[32 * 64];
  int t = threadIdx.x;
  for (int idx = t; idx < 2048; idx += 256) Ws[idx] = W[idx];
  __syncthreads();
  int i = blockIdx.x * 256 + t;
  if (i >= n) return;
  float x[32];
  const float4* xp = (const float4*)(X + (size_t)i * 32);
  #pragma unroll
  for (int q = 0; q < 8; ++q) { float4 v = xp[q]; x[q*4] = v.x; x[q*4+1] = v.y; x[q*4+2] = v.z; x[q*4+3] = v.w; }
  float acc[64];
  #pragma unroll
  for (int c = 0; c < 64; ++c) acc[c] = 0.f;
  for (int k = 0; k < 32; ++k) {
    float xk = x[k];
    #pragma unroll
    for (int c = 0; c < 64; ++c) acc[c] += xk * Ws[k * 64 + c];
  }
  float s1v = 0.f, s2v = 0.f;
  #pragma unroll
  for (int c = 0; c < 64; ++c) { float a = fabsf(acc[c]); s1v += a * a1[c]; s2v += a * a2[c]; }
  float4* hp = (float4*)(H + (size_t)i * 64);
  #pragma unroll
  for (int q = 0; q < 16; ++q) hp[q] = make_float4(acc[q*4], acc[q*4+1], acc[q*4+2], acc[q*4+3]);
  s1o[i] = s1v; s2o[i] = s2v;
}

// ---------------- pooling ----------------
__global__ void graph_bounds_k(const int* __restrict__ batch, int n, int* __restrict__ off) {
  int g = blockIdx.x * 256 + threadIdx.x;
  if (g > N_GRAPHS) return;
  int lo = 0, hi = n;
  while (lo < hi) { int mid = (lo + hi) >> 1; if (batch[mid] < g) lo = mid + 1; else hi = mid; }
  off[g] = lo;
}

__global__ __launch_bounds__(256) void pool_k(const float* __restrict__ X, const int* __restrict__ off,
                                              float* __restrict__ out) {
  __shared__ float sm[256];
  int g = blockIdx.x;
  int beg = off[g], end = off[g + 1];
  int t = threadIdx.x;
  int f = t & 63, j = t >> 6;
  float acc = 0.f;
  for (int r = beg + j; r < end; r += 4) acc += X[(size_t)r * 64 + f];
  sm[t] = acc;
  __syncthreads();
  if (j == 0) {
    float ssum = sm[f] + sm[64 + f] + sm[128 + f] + sm[192 + f];
    float cnt = (float)(end - beg);
    float p = ssum / fmaxf(cnt, 1.f);
    float m = p;
    #pragma unroll
    for (int d = 32; d; d >>= 1) m = fmaxf(m, __shfl_xor(m, d));
    float e = __expf(p - m);
    float se = e;
    #pragma unroll
    for (int d = 32; d; d >>= 1) se += __shfl_xor(se, d);
    out[g * 64 + f] = e / se;
  }
}

extern "C" void kernel_launch(void* const* d_in, const int* in_sizes, int n_in,
                              void* d_out, int out_size, void* d_ws, size_t ws_size,
                              hipStream_t stream) {
  const float* X1    = (const float*)d_in[0];
  const int*   idxup = (const int*)d_in[1];
  const float* valup = (const float*)d_in[2];
  const int*   idxdn = (const int*)d_in[3];
  const float* valdn = (const float*)d_in[4];
  const int*   batch = (const int*)d_in[5];
  const float* W1  = (const float*)d_in[6];
  const float* a11 = (const float*)d_in[7];
  const float* a21 = (const float*)d_in[8];
  const float* W2  = (const float*)d_in[9];
  const float* a12 = (const float*)d_in[10];
  const float* a22 = (const float*)d_in[11];
  const float* W4  = (const float*)d_in[12];
  const float* a14 = (const float*)d_in[13];
  const float* a24 = (const float*)d_in[14];
  float* out = (float*)d_out;

  const int N = N_NODES;
  char* p = (char*)d_ws;
  auto alloc = [&](size_t bytes) { char* q = p; p += (bytes + 255) & ~(size_t)255; return q; };
  int*   rp[2]  = { (int*)alloc((size_t)(N + 1) * 4), (int*)alloc((size_t)(N + 1) * 4) };
  int*   nxt[2] = { (int*)alloc((size_t)N * 4), (int*)alloc((size_t)N * 4) };
  int*   blk[2] = { (int*)alloc(128 * 4), (int*)alloc(128 * 4) };
  int*   csb[2] = { (int*)alloc((size_t)NNZ_CNT * 4), (int*)alloc((size_t)NNZ_CNT * 4) };
  float* vsb[2] = { (float*)alloc((size_t)NNZ_CNT * 4), (float*)alloc((size_t)NNZ_CNT * 4) };
  float* sbuf = (float*)alloc((size_t)4 * N * 4);
  float* hbuf = (float*)alloc((size_t)N * 64 * 4);
  float* Xa   = (float*)alloc((size_t)N * 32 * 4);
  float* X4   = (float*)alloc((size_t)N * 64 * 4);
  int*   goff = (int*)alloc((N_GRAPHS + 1) * 4);

  const int*   rows[2] = { idxup, idxdn };
  const int*   cols[2] = { idxup + NNZ_CNT, idxdn + NNZ_CNT };
  const float* vals[2] = { valup, valdn };

  const int SCAN_B = (N + 2047) / 2048;
  for (int L = 0; L < 2; ++L) {
    hipMemsetAsync(nxt[L], 0, (size_t)N * 4, stream);
    count_rows_k<<<NNZ_CNT / 256, 256, 0, stream>>>(rows[L], NNZ_CNT, nxt[L]);
    scan_local_k<<<SCAN_B, 256, 0, stream>>>(nxt[L], N, rp[L], blk[L]);
    scan_blocks_k<<<1, 128, 0, stream>>>(blk[L], SCAN_B);
    scan_add_k<<<(N + 255) / 256, 256, 0, stream>>>(rp[L], blk[L], N, nxt[L], NNZ_CNT);
    scatter_k<<<NNZ_CNT / 256, 256, 0, stream>>>(rows[L], cols[L], vals[L], NNZ_CNT, nxt[L], csb[L], vsb[L]);
  }

  // layer 1
  gemm1_k<<<(N + 127) / 128, 256, 0, stream>>>(X1, W1, hbuf, N);
  s_l1_k<<<(N + 255) / 256, 256, 0, stream>>>(hbuf, a11, a21, sbuf, N);
  spmm16_k<<<N / 4, 256, 0, stream>>>(rp[0], csb[0], vsb[0], hbuf,      sbuf,         sbuf + N,     Xa,      N);
  spmm16_k<<<N / 4, 256, 0, stream>>>(rp[1], csb[1], vsb[1], hbuf + 16, sbuf + 2 * N, sbuf + 3 * N, Xa + 16, N);

  // layer 2
  gemm2_k<<<(N + 255) / 256, 256, 0, stream>>>(Xa, W2, a12, a22, hbuf, sbuf, N);
  spmm16_k<<<N / 4, 256, 0, stream>>>(rp[0], csb[0], vsb[0], hbuf,      sbuf,         sbuf + N,     Xa,      N);
  spmm16_k<<<N / 4, 256, 0, stream>>>(rp[1], csb[1], vsb[1], hbuf + 16, sbuf + 2 * N, sbuf + 3 * N, Xa + 16, N);

  // layer 4 (heads summed, then relu)
  gemm4_k<<<(N + 255) / 256, 256, 0, stream>>>(Xa, W4,        a14,      a24,      hbuf, sbuf, sbuf + N, N);
  spmm64_k<0><<<N / 4, 256, 0, stream>>>(rp[0], csb[0], vsb[0], hbuf, sbuf, sbuf + N, X4, N);
  gemm4_k<<<(N + 255) / 256, 256, 0, stream>>>(Xa, W4 + 2048, a14 + 64, a24 + 64, hbuf, sbuf, sbuf + N, N);
  spmm64_k<1><<<N / 4, 256, 0, stream>>>(rp[1], csb[1], vsb[1], hbuf, sbuf, sbuf + N, X4, N);

  // pool + softmax
  graph_bounds_k<<<2, 256, 0, stream>>>(batch, N, goff);
  pool_k<<<N_GRAPHS, 256, 0, stream>>>(X4, goff, out);
}

// Round 2
// 1685.001 us; speedup vs baseline: 1.4128x; 1.4128x over previous
//
#include <hip/hip_runtime.h>
#include <hip/hip_bf16.h>
#include <math.h>

#define N_NODES  200000
#define NNZ_CNT  3200000
#define N_GRAPHS 256

// ---------------- CSR build ----------------
__global__ void count_rows_k(const int* __restrict__ rows, int nnz, int* __restrict__ cnt) {
  int i = blockIdx.x * 256 + threadIdx.x;
  if (i < nnz) atomicAdd(&cnt[rows[i]], 1);
}

__global__ void scan_local_k(const int* __restrict__ cnt, int n, int* __restrict__ out, int* __restrict__ blk) {
  __shared__ int wsum[4];
  int t = threadIdx.x;
  int base = blockIdx.x * 2048 + t * 8;
  int v[8]; int s = 0;
  #pragma unroll
  for (int j = 0; j < 8; ++j) { int idx = base + j; v[j] = (idx < n) ? cnt[idx] : 0; s += v[j]; }
  int lane = t & 63, w = t >> 6;
  int x = s;
  #pragma unroll
  for (int d = 1; d < 64; d <<= 1) { int y = __shfl_up(x, d); if (lane >= d) x += y; }
  if (lane == 63) wsum[w] = x;
  __syncthreads();
  int wofs = 0;
  for (int i2 = 0; i2 < w; ++i2) wofs += wsum[i2];
  int run = wofs + x - s;
  #pragma unroll
  for (int j = 0; j < 8; ++j) { int idx = base + j; if (idx < n) out[idx] = run; run += v[j]; }
  if (t == 255) blk[blockIdx.x] = wofs + x;
}

__global__ void scan_blocks_k(int* __restrict__ blk, int B) {
  __shared__ int wsum[2];
  int t = threadIdx.x;
  int v = (t < B) ? blk[t] : 0;
  int lane = t & 63, w = t >> 6;
  int x = v;
  #pragma unroll
  for (int d = 1; d < 64; d <<= 1) { int y = __shfl_up(x, d); if (lane >= d) x += y; }
  if (lane == 63) wsum[w] = x;
  __syncthreads();
  int wofs = (w == 1) ? wsum[0] : 0;
  if (t < B) blk[t] = wofs + x - v;
}

__global__ void scan_add_k(int* __restrict__ out, const int* __restrict__ blk, int n,
                           int* __restrict__ nxt, int total) {
  int i = blockIdx.x * 256 + threadIdx.x;
  if (i < n) { int v = out[i] + blk[i >> 11]; out[i] = v; nxt[i] = v; }
  if (i == 0) out[n] = total;
}

__global__ void scatter_k(const int* __restrict__ rows, const int* __restrict__ cols,
                          const float* __restrict__ vals, int nnz, int* __restrict__ nxt,
                          int* __restrict__ cs, float* __restrict__ vs) {
  int i = blockIdx.x * 256 + threadIdx.x;
  if (i < nnz) {
    int r = rows[i];
    int p = atomicAdd(&nxt[r], 1);
    cs[p] = cols[i];
    vs[p] = vals[i];
  }
}

// ---------------- layer-1 GEMM: [N,128] @ [128,32] (heads concat) ----------------
__global__ __launch_bounds__(256) void gemm1_k(const float* __restrict__ X, const float* __restrict__ W,
                                               float* __restrict__ H, int n) {
  __shared__ float Ws[128 * 32];
  __shared__ float Xs[128 * 33];
  int t = threadIdx.x;
  for (int idx = t; idx < 4096; idx += 256) {
    int hh = idx >> 11, rem = idx & 2047, k = rem >> 4, f = rem & 15;
    Ws[k * 32 + hh * 16 + f] = W[idx];
  }
  int r0 = blockIdx.x * 128;
  int rt = t >> 3, ct = t & 7;
  float acc[4][4];
  #pragma unroll
  for (int i = 0; i < 4; ++i)
    #pragma unroll
    for (int j = 0; j < 4; ++j) acc[i][j] = 0.f;
  for (int k0 = 0; k0 < 128; k0 += 32) {
    __syncthreads();
    #pragma unroll
    for (int pp = 0; pp < 4; ++pp) {
      int f4 = pp * 256 + t;
      int row = f4 >> 3, q = f4 & 7;
      int rr = r0 + row;
      float4 v = make_float4(0.f, 0.f, 0.f, 0.f);
      if (rr < n) v = *(const float4*)&X[rr * 128 + k0 + q * 4];
      Xs[row * 33 + q * 4 + 0] = v.x;
      Xs[row * 33 + q * 4 + 1] = v.y;
      Xs[row * 33 + q * 4 + 2] = v.z;
      Xs[row * 33 + q * 4 + 3] = v.w;
    }
    __syncthreads();
    #pragma unroll
    for (int kk = 0; kk < 32; ++kk) {
      int k = k0 + kk;
      float4 wv = *(const float4*)&Ws[k * 32 + ct * 4];
      float xv[4];
      #pragma unroll
      for (int i = 0; i < 4; ++i) xv[i] = Xs[(rt * 4 + i) * 33 + kk];
      #pragma unroll
      for (int i = 0; i < 4; ++i) {
        acc[i][0] += xv[i] * wv.x;
        acc[i][1] += xv[i] * wv.y;
        acc[i][2] += xv[i] * wv.z;
        acc[i][3] += xv[i] * wv.w;
      }
    }
  }
  #pragma unroll
  for (int i = 0; i < 4; ++i) {
    int rr = r0 + rt * 4 + i;
    if (rr < n)
      *(float4*)&H[rr * 32 + ct * 4] = make_float4(acc[i][0], acc[i][1], acc[i][2], acc[i][3]);
  }
}

// ---------------- per-row attention scores s1,s2 for layer 1 ----------------
__global__ void s_l1_k(const float* __restrict__ H, const float* __restrict__ a1,
                       const float* __restrict__ a2, float* __restrict__ s, int n) {
  int i = blockIdx.x * 256 + threadIdx.x;
  if (i >= n) return;
  const float* h = H + (size_t)i * 32;
  float s1u = 0.f, s2u = 0.f, s1d = 0.f, s2d = 0.f;
  #pragma unroll
  for (int f = 0; f < 16; ++f) {
    float au = fabsf(h[f]);
    s1u += au * a1[f]; s2u += au * a2[f];
    float ad = fabsf(h[16 + f]);
    s1d += ad * a1[16 + f]; s2d += ad * a2[16 + f];
  }
  s[i] = s1u; s[n + i] = s2u; s[2 * n + i] = s1d; s[3 * n + i] = s2d;
}

// ---------------- fused softmax+SpMM, f_out=16, both heads in one launch ----------------
__global__ __launch_bounds__(256) void spmm16_dual_k(
    const int* __restrict__ rp0, const int* __restrict__ cs0, const float* __restrict__ vs0,
    const int* __restrict__ rp1, const int* __restrict__ cs1, const float* __restrict__ vs1,
    const float* __restrict__ H, const float* __restrict__ s, float* __restrict__ out, int n) {
  int wid2 = (blockIdx.x * 256 + threadIdx.x) >> 6;
  if (wid2 >= 2 * n) return;
  int lane = threadIdx.x & 63;
  int h = (wid2 >= n) ? 1 : 0;
  int wid = wid2 - h * n;
  const int*   rp = h ? rp1 : rp0;
  const int*   cs = h ? cs1 : cs0;
  const float* vs = h ? vs1 : vs0;
  const float* s1 = s + (size_t)(2 * h) * n;
  const float* s2 = s + (size_t)(2 * h + 1) * n;
  int ho = h * 16;
  int beg = rp[wid], end = rp[wid + 1];
  int cnt = end - beg;
  float s1r = s1[wid];
  float4 acc = make_float4(0.f, 0.f, 0.f, 0.f);
  int j = lane >> 2, f = lane & 3;
  if (cnt <= 64) {
    int cl = 0; float vl = 0.f, sc = -1e30f;
    if (lane < cnt) {
      cl = cs[beg + lane];
      vl = vs[beg + lane];
      sc = s1r + s2[cl];
    }
    float m = sc;
    #pragma unroll
    for (int d = 32; d; d >>= 1) m = fmaxf(m, __shfl_xor(m, d));
    float el = (lane < cnt) ? __expf(sc - m) : 0.f;
    float es = el;
    #pragma unroll
    for (int d = 32; d; d >>= 1) es += __shfl_xor(es, d);
    float att = (cnt > 0) ? el * vl / es : 0.f;
    for (int t = 0; t < cnt; t += 16) {
      int e = t + j;
      float a = __shfl(att, e);
      int   c = __shfl(cl, e);
      if (e < cnt) {
        const float4 hv = *(const float4*)&H[(size_t)c * 32 + ho + f * 4];
        acc.x += a * hv.x; acc.y += a * hv.y; acc.z += a * hv.z; acc.w += a * hv.w;
      }
    }
  } else {
    float vmax = -1e30f;
    for (int e = beg + lane; e < end; e += 64) vmax = fmaxf(vmax, s1r + s2[cs[e]]);
    #pragma unroll
    for (int d = 32; d; d >>= 1) vmax = fmaxf(vmax, __shfl_xor(vmax, d));
    float esum = 0.f;
    for (int e = beg + lane; e < end; e += 64) esum += __expf(s1r + s2[cs[e]] - vmax);
    #pragma unroll
    for (int d = 32; d; d >>= 1) esum += __shfl_xor(esum, d);
    float inv = 1.f / esum;
    for (int t = 0; t < cnt; t += 16) {
      int e = t + j;
      if (e < cnt) {
        int c = cs[beg + e];
        float a = __expf(s1r + s2[c] - vmax) * inv * vs[beg + e];
        const float4 hv = *(const float4*)&H[(size_t)c * 32 + ho + f * 4];
        acc.x += a * hv.x; acc.y += a * hv.y; acc.z += a * hv.z; acc.w += a * hv.w;
      }
    }
  }
  #pragma unroll
  for (int d = 4; d < 64; d <<= 1) {
    acc.x += __shfl_xor(acc.x, d);
    acc.y += __shfl_xor(acc.y, d);
    acc.z += __shfl_xor(acc.z, d);
    acc.w += __shfl_xor(acc.w, d);
  }
  if (lane < 4)
    *(float4*)&out[(size_t)wid * 32 + ho + lane * 4] =
      make_float4(fmaxf(acc.x, 0.f), fmaxf(acc.y, 0.f), fmaxf(acc.z, 0.f), fmaxf(acc.w, 0.f));
}

// ---------------- fused softmax+SpMM, f_out=64 ----------------
template <int MODE>
__global__ __launch_bounds__(256) void spmm64_k(const int* __restrict__ rp, const int* __restrict__ cs,
    const float* __restrict__ vs, const float* __restrict__ H, const float* __restrict__ s1,
    const float* __restrict__ s2, float* __restrict__ out, int n) {
  int wid = (blockIdx.x * 256 + threadIdx.x) >> 6;
  if (wid >= n) return;
  int lane = threadIdx.x & 63;
  int beg = rp[wid], end = rp[wid + 1];
  int cnt = end - beg;
  float s1r = s1[wid];
  float4 acc = make_float4(0.f, 0.f, 0.f, 0.f);
  int j = lane >> 4, f = lane & 15;
  if (cnt <= 64) {
    int cl = 0; float vl = 0.f, sc = -1e30f;
    if (lane < cnt) {
      cl = cs[beg + lane];
      vl = vs[beg + lane];
      sc = s1r + s2[cl];
    }
    float m = sc;
    #pragma unroll
    for (int d = 32; d; d >>= 1) m = fmaxf(m, __shfl_xor(m, d));
    float el = (lane < cnt) ? __expf(sc - m) : 0.f;
    float es = el;
    #pragma unroll
    for (int d = 32; d; d >>= 1) es += __shfl_xor(es, d);
    float att = (cnt > 0) ? el * vl / es : 0.f;
    for (int t = 0; t < cnt; t += 4) {
      int e = t + j;
      float a = __shfl(att, e);
      int   c = __shfl(cl, e);
      if (e < cnt) {
        const float4 hv = *(const float4*)&H[(size_t)c * 64 + f * 4];
        acc.x += a * hv.x; acc.y += a * hv.y; acc.z += a * hv.z; acc.w += a * hv.w;
      }
    }
  } else {
    float vmax = -1e30f;
    for (int e = beg + lane; e < end; e += 64) vmax = fmaxf(vmax, s1r + s2[cs[e]]);
    #pragma unroll
    for (int d = 32; d; d >>= 1) vmax = fmaxf(vmax, __shfl_xor(vmax, d));
    float esum = 0.f;
    for (int e = beg + lane; e < end; e += 64) esum += __expf(s1r + s2[cs[e]] - vmax);
    #pragma unroll
    for (int d = 32; d; d >>= 1) esum += __shfl_xor(esum, d);
    float inv = 1.f / esum;
    for (int t = 0; t < cnt; t += 4) {
      int e = t + j;
      if (e < cnt) {
        int c = cs[beg + e];
        float a = __expf(s1r + s2[c] - vmax) * inv * vs[beg + e];
        const float4 hv = *(const float4*)&H[(size_t)c * 64 + f * 4];
        acc.x += a * hv.x; acc.y += a * hv.y; acc.z += a * hv.z; acc.w += a * hv.w;
      }
    }
  }
  #pragma unroll
  for (int d = 16; d < 64; d <<= 1) {
    acc.x += __shfl_xor(acc.x, d);
    acc.y += __shfl_xor(acc.y, d);
    acc.z += __shfl_xor(acc.z, d);
    acc.w += __shfl_xor(acc.w, d);
  }
  if (lane < 16) {
    size_t o = (size_t)wid * 64 + lane * 4;
    if (MODE == 0) {
      *(float4*)&out[o] = acc;
    } else {
      float4 prev = *(const float4*)&out[o];
      *(float4*)&out[o] = make_float4(fmaxf(prev.x + acc.x, 0.f), fmaxf(prev.y + acc.y, 0.f),
                                      fmaxf(prev.z + acc.z, 0.f), fmaxf(prev.w + acc.w, 0.f));
    }
  }
}

// ---------------- layer-2 GEMM [N,32]@[32,32] + fused s1/s2 ----------------
__global__ __launch_bounds__(256) void gemm2_k(const float* __restrict__ X, const float* __restrict__ W,
    const float* __restrict__ a1, const float* __restrict__ a2, float* __restrict__ H,
    float* __restrict__ s, int n) {
  __shared__ float Ws[32 * 32];
  int t = threadIdx.x;
  for (int idx = t; idx < 1024; idx += 256) {
    int hh = idx >> 9, rem = idx & 511, k = rem >> 4, f = rem & 15;
    Ws[k * 32 + hh * 16 + f] = W[idx];
  }
  __syncthreads();
  int i = blockIdx.x * 256 + t;
  if (i >= n) return;
  float x[32];
  const float4* xp = (const float4*)(X + (size_t)i * 32);
  #pragma unroll
  for (int q = 0; q < 8; ++q) { float4 v = xp[q]; x[q*4] = v.x; x[q*4+1] = v.y; x[q*4+2] = v.z; x[q*4+3] = v.w; }
  float acc[32];
  #pragma unroll
  for (int c = 0; c < 32; ++c) acc[c] = 0.f;
  #pragma unroll 8
  for (int k = 0; k < 32; ++k) {
    float xk = x[k];
    #pragma unroll
    for (int c = 0; c < 32; ++c) acc[c] += xk * Ws[k * 32 + c];
  }
  float s1u = 0.f, s2u = 0.f, s1d = 0.f, s2d = 0.f;
  #pragma unroll
  for (int f = 0; f < 16; ++f) {
    float au = fabsf(acc[f]);      s1u += au * a1[f];      s2u += au * a2[f];
    float ad = fabsf(acc[16 + f]); s1d += ad * a1[16 + f]; s2d += ad * a2[16 + f];
  }
  float4* hp = (float4*)(H + (size_t)i * 32);
  #pragma unroll
  for (int q = 0; q < 8; ++q) hp[q] = make_float4(acc[q*4], acc[q*4+1], acc[q*4+2], acc[q*4+3]);
  s[i] = s1u; s[n + i] = s2u; s[2 * n + i] = s1d; s[3 * n + i] = s2d;
}

// ---------------- layer-4 GEMM [N,32]@[32,64] per head + fused s1/s2 ----------------
__global__ __launch_bounds__(256) void gemm4_k(const float* __restrict__ X, const float* __restrict__ W,
    const float* __restrict__ a1, const float* __restrict__ a2, float* __restrict__ H,
    float* __restrict__ s1o, float* __restrict__ s2o, int n) {
  __shared__ float Ws[32 * 64];
  int t = threadIdx.x;
  for (int idx = t; idx < 2048; idx += 256) Ws[idx] = W[idx];
  __syncthreads();
  int i = blockIdx.x * 256 + t;
  if (i >= n) return;
  float x[32];
  const float4* xp = (const float4*)(X + (size_t)i * 32);
  #pragma unroll
  for (int q = 0; q < 8; ++q) { float4 v = xp[q]; x[q*4] = v.x; x[q*4+1] = v.y; x[q*4+2] = v.z; x[q*4+3] = v.w; }
  float acc[64];
  #pragma unroll
  for (int c = 0; c < 64; ++c) acc[c] = 0.f;
  for (int k = 0; k < 32; ++k) {
    float xk = x[k];
    #pragma unroll
    for (int c = 0; c < 64; ++c) acc[c] += xk * Ws[k * 64 + c];
  }
  float s1v = 0.f, s2v = 0.f;
  #pragma unroll
  for (int c = 0; c < 64; ++c) { float a = fabsf(acc[c]); s1v += a * a1[c]; s2v += a * a2[c]; }
  float4* hp = (float4*)(H + (size_t)i * 64);
  #pragma unroll
  for (int q = 0; q < 16; ++q) hp[q] = make_float4(acc[q*4], acc[q*4+1], acc[q*4+2], acc[q*4+3]);
  s1o[i] = s1v; s2o[i] = s2v;
}

// ---------------- pooling ----------------
__global__ void graph_bounds_k(const int* __restrict__ batch, int n, int* __restrict__ off) {
  int g = blockIdx.x * 256 + threadIdx.x;
  if (g > N_GRAPHS) return;
  int lo = 0, hi = n;
  while (lo < hi) { int mid = (lo + hi) >> 1; if (batch[mid] < g) lo = mid + 1; else hi = mid; }
  off[g] = lo;
}

__global__ __launch_bounds__(256) void pool_k(const float* __restrict__ X, const int* __restrict__ off,
                                              float* __restrict__ out) {
  __shared__ float sm[256];
  int g = blockIdx.x;
  int beg = off[g], end = off[g + 1];
  int t = threadIdx.x;
  int f = t & 63, j = t >> 6;
  float acc = 0.f;
  for (int r = beg + j; r < end; r += 4) acc += X[(size_t)r * 64 + f];
  sm[t] = acc;
  __syncthreads();
  if (j == 0) {
    float ssum = sm[f] + sm[64 + f] + sm[128 + f] + sm[192 + f];
    float cnt = (float)(end - beg);
    float p = ssum / fmaxf(cnt, 1.f);
    float m = p;
    #pragma unroll
    for (int d = 32; d; d >>= 1) m = fmaxf(m, __shfl_xor(m, d));
    float e = __expf(p - m);
    float se = e;
    #pragma unroll
    for (int d = 32; d; d >>= 1) se += __shfl_xor(se, d);
    out[g * 64 + f] = e / se;
  }
}

extern "C" void kernel_launch(void* const* d_in, const int* in_sizes, int n_in,
                              void* d_out, int out_size, void* d_ws, size_t ws_size,
                              hipStream_t stream) {
  const float* X1    = (const float*)d_in[0];
  const int*   idxup = (const int*)d_in[1];
  const float* valup = (const float*)d_in[2];
  const int*   idxdn = (const int*)d_in[3];
  const float* valdn = (const float*)d_in[4];
  const int*   batch = (const int*)d_in[5];
  const float* W1  = (const float*)d_in[6];
  const float* a11 = (const float*)d_in[7];
  const float* a21 = (const float*)d_in[8];
  const float* W2  = (const float*)d_in[9];
  const float* a12 = (const float*)d_in[10];
  const float* a22 = (const float*)d_in[11];
  const float* W4  = (const float*)d_in[12];
  const float* a14 = (const float*)d_in[13];
  const float* a24 = (const float*)d_in[14];
  float* out = (float*)d_out;

  const int N = N_NODES;
  char* p = (char*)d_ws;
  auto alloc = [&](size_t bytes) { char* q = p; p += (bytes + 255) & ~(size_t)255; return q; };
  int*   rp[2]  = { (int*)alloc((size_t)(N + 1) * 4), (int*)alloc((size_t)(N + 1) * 4) };
  int*   nxt[2] = { (int*)alloc((size_t)N * 4), (int*)alloc((size_t)N * 4) };
  int*   blk[2] = { (int*)alloc(128 * 4), (int*)alloc(128 * 4) };
  int*   csb[2] = { (int*)alloc((size_t)NNZ_CNT * 4), (int*)alloc((size_t)NNZ_CNT * 4) };
  float* vsb[2] = { (float*)alloc((size_t)NNZ_CNT * 4), (float*)alloc((size_t)NNZ_CNT * 4) };
  float* sbuf = (float*)alloc((size_t)4 * N * 4);
  float* hbuf = (float*)alloc((size_t)N * 64 * 4);
  float* Xa   = (float*)alloc((size_t)N * 32 * 4);
  float* X4   = (float*)alloc((size_t)N * 64 * 4);
  int*   goff = (int*)alloc((N_GRAPHS + 1) * 4);

  const int*   rows[2] = { idxup, idxdn };
  const int*   cols[2] = { idxup + NNZ_CNT, idxdn + NNZ_CNT };
  const float* vals[2] = { valup, valdn };

  const int SCAN_B = (N + 2047) / 2048;
  for (int L = 0; L < 2; ++L) {
    hipMemsetAsync(nxt[L], 0, (size_t)N * 4, stream);
    count_rows_k<<<NNZ_CNT / 256, 256, 0, stream>>>(rows[L], NNZ_CNT, nxt[L]);
    scan_local_k<<<SCAN_B, 256, 0, stream>>>(nxt[L], N, rp[L], blk[L]);
    scan_blocks_k<<<1, 128, 0, stream>>>(blk[L], SCAN_B);
    scan_add_k<<<(N + 255) / 256, 256, 0, stream>>>(rp[L], blk[L], N, nxt[L], NNZ_CNT);
    scatter_k<<<NNZ_CNT / 256, 256, 0, stream>>>(rows[L], cols[L], vals[L], NNZ_CNT, nxt[L], csb[L], vsb[L]);
  }

  // layer 1
  gemm1_k<<<(N + 127) / 128, 256, 0, stream>>>(X1, W1, hbuf, N);
  s_l1_k<<<(N + 255) / 256, 256, 0, stream>>>(hbuf, a11, a21, sbuf, N);
  spmm16_dual_k<<<(2 * N + 3) / 4, 256, 0, stream>>>(rp[0], csb[0], vsb[0], rp[1], csb[1], vsb[1],
                                                     hbuf, sbuf, Xa, N);

  // layer 2
  gemm2_k<<<(N + 255) / 256, 256, 0, stream>>>(Xa, W2, a12, a22, hbuf, sbuf, N);
  spmm16_dual_k<<<(2 * N + 3) / 4, 256, 0, stream>>>(rp[0], csb[0], vsb[0], rp[1], csb[1], vsb[1],
                                                     hbuf, sbuf, Xa, N);

  // layer 4 (heads summed, then relu)
  gemm4_k<<<(N + 255) / 256, 256, 0, stream>>>(Xa, W4,        a14,      a24,      hbuf, sbuf, sbuf + N, N);
  spmm64_k<0><<<(N + 3) / 4, 256, 0, stream>>>(rp[0], csb[0], vsb[0], hbuf, sbuf, sbuf + N, X4, N);
  gemm4_k<<<(N + 255) / 256, 256, 0, stream>>>(Xa, W4 + 2048, a14 + 64, a24 + 64, hbuf, sbuf, sbuf + N, N);
  spmm64_k<1><<<(N + 3) / 4, 256, 0, stream>>>(rp[1], csb[1], vsb[1], hbuf, sbuf, sbuf + N, X4, N);

  // pool + softmax
  graph_bounds_k<<<2, 256, 0, stream>>>(batch, N, goff);
  pool_k<<<N_GRAPHS, 256, 0, stream>>>(X4, goff, out);
}